// Round 3
// baseline (238.466 us; speedup 1.0000x reference)
//
#include <hip/hip_runtime.h>
#include <cstdint>

#define DEV __device__ __forceinline__

typedef __bf16 bf16x4 __attribute__((ext_vector_type(4)));
typedef __bf16 bf16x8 __attribute__((ext_vector_type(8)));
typedef float  floatx4 __attribute__((ext_vector_type(4)));

constexpr int BB = 8, NSEQ = 1024, DMODEL = 768, NH = 12, HD = 64;
constexpr int MTOK = BB * NSEQ;   // 8192 tokens
constexpr int NQKV = 3 * DMODEL;  // 2304
constexpr float CS = 0.18033688011112042f;  // (1/sqrt(64)) * log2(e), folded into Q

DEV void async_copy16(void* lds, const void* g) {
    // global -> LDS direct copy, 16B/lane. LDS dest must be wave-base + lane*16.
    __builtin_amdgcn_global_load_lds(
        (__attribute__((address_space(1))) void*)(const_cast<void*>(g)),
        (__attribute__((address_space(3))) void*)lds,
        16, 0, 0);
}

DEV floatx4 mfma16(bf16x8 a, bf16x8 b, floatx4 c) {
    return __builtin_amdgcn_mfma_f32_16x16x32_bf16(a, b, c, 0, 0, 0);
}

// ---------------- x fp32 -> bf16 ----------------
__global__ __launch_bounds__(256) void k_convert_x(const float* __restrict__ x,
                                                   __bf16* __restrict__ xb) {
    int i = (blockIdx.x * 256 + threadIdx.x) * 4;  // grid sized exactly
    float4 v = *(const float4*)(x + i);
    bf16x4 o;
    o[0] = (__bf16)v.x; o[1] = (__bf16)v.y; o[2] = (__bf16)v.z; o[3] = (__bf16)v.w;
    *(bf16x4*)(xb + i) = o;
}

// ---------------- bias concat (q|k|v) fp32 ----------------
__global__ __launch_bounds__(256) void k_bias(const float* __restrict__ bq,
                                              const float* __restrict__ bk,
                                              const float* __restrict__ bv,
                                              float* __restrict__ out) {
    int i = blockIdx.x * 256 + threadIdx.x;  // grid = 9 -> 2304 exact
    if (i < 768) out[i] = bq[i];
    else if (i < 1536) out[i] = bk[i - 768];
    else if (i < 2304) out[i] = bv[i - 1536];
}

// ---------------- W [K,N] fp32 -> Wt [N,K] bf16 (z: 0=q 1=k 2=v 3=o) ----------------
__global__ __launch_bounds__(256) void k_transpose_w(const float* __restrict__ Wq,
                                                     const float* __restrict__ Wk,
                                                     const float* __restrict__ Wv,
                                                     const float* __restrict__ Wo,
                                                     __bf16* __restrict__ wtqkv,
                                                     __bf16* __restrict__ wto) {
    __shared__ float tile[32][33];
    int z = blockIdx.z;
    const float* W = (z == 0) ? Wq : (z == 1) ? Wk : (z == 2) ? Wv : Wo;
    int k0 = blockIdx.x * 32, n0 = blockIdx.y * 32;
    int tx = threadIdx.x & 31, ty = threadIdx.x >> 5;
#pragma unroll
    for (int p = 0; p < 4; p++)
        tile[ty + 8 * p][tx] = W[(size_t)(k0 + ty + 8 * p) * 768 + n0 + tx];
    __syncthreads();
    __bf16* out = (z < 3) ? (wtqkv + (size_t)z * 768 * 768) : wto;
#pragma unroll
    for (int p = 0; p < 4; p++)
        out[(size_t)(n0 + ty + 8 * p) * 768 + k0 + tx] = (__bf16)tile[tx][ty + 8 * p];
}

// ---------------- GEMM: C[M,Nn] = A[M,768] @ Bt[Nn,768]^T + bias ----------------
// BM=BN=128, BK=64, 4 waves each 64x64 (4x4 acc of 16x16x32 MFMA).
// QKV=true: scale Q cols by CS; route V cols (>=1536) transposed into vtb[b,h,hd,tok].
template <typename OutT, bool QKV>
__global__ __launch_bounds__(256) void k_gemm(const __bf16* __restrict__ A,
                                              const __bf16* __restrict__ Bt,
                                              const float* __restrict__ bias,
                                              OutT* __restrict__ C, int Nn,
                                              __bf16* __restrict__ vtb) {
    __shared__ __align__(16) __bf16 As[128 * 64];
    __shared__ __align__(16) __bf16 Bs[128 * 64];
    int t = threadIdx.x, lane = t & 63, w = t >> 6;
    int quad = lane >> 4, n16 = lane & 15;
    int wm = w & 1, wn = w >> 1;
    int m0 = blockIdx.x * 128, n0 = blockIdx.y * 128;
    floatx4 acc[4][4] = {};

    for (int k0 = 0; k0 < 768; k0 += 64) {
        __syncthreads();
#pragma unroll
        for (int i = 0; i < 4; i++) {  // stage A tile 128x64 (16KB)
            int off = t + i * 256;
            int row = off >> 3, pc = off & 7;
            int c = pc ^ (row & 7);
            async_copy16(&As[row * 64 + pc * 8],
                         &A[(size_t)(m0 + row) * 768 + k0 + c * 8]);
        }
#pragma unroll
        for (int i = 0; i < 4; i++) {  // stage B tile 128x64
            int off = t + i * 256;
            int row = off >> 3, pc = off & 7;
            int c = pc ^ (row & 7);
            async_copy16(&Bs[row * 64 + pc * 8],
                         &Bt[(size_t)(n0 + row) * 768 + k0 + c * 8]);
        }
        __builtin_amdgcn_s_waitcnt(0);  // drain global_load_lds before barrier
        __syncthreads();
#pragma unroll
        for (int kfi = 0; kfi < 2; kfi++) {
            bf16x8 a[4], bfr[4];
#pragma unroll
            for (int rt = 0; rt < 4; rt++) {
                int row = wm * 64 + rt * 16 + n16;
                a[rt] = *(const bf16x8*)&As[row * 64 + ((quad + 4 * kfi) ^ (row & 7)) * 8];
            }
#pragma unroll
            for (int ct = 0; ct < 4; ct++) {
                int row = wn * 64 + ct * 16 + n16;
                bfr[ct] = *(const bf16x8*)&Bs[row * 64 + ((quad + 4 * kfi) ^ (row & 7)) * 8];
            }
#pragma unroll
            for (int rt = 0; rt < 4; rt++)
#pragma unroll
                for (int ct = 0; ct < 4; ct++)
                    acc[rt][ct] = mfma16(a[rt], bfr[ct], acc[rt][ct]);
        }
    }
    // epilogue: C/D layout col=lane&15, row=quad*4+reg
#pragma unroll
    for (int ct = 0; ct < 4; ct++) {
        int col = n0 + wn * 64 + ct * 16 + n16;
        float bs = bias[col];
        if (QKV && col >= 1536) {
            // V region -> vtb[b,h,hd,tok], 4 consecutive tokens per b64 store
            int vcol = col - 1536;
            int hh = vcol >> 6, hd = vcol & 63;
#pragma unroll
            for (int rt = 0; rt < 4; rt++) {
                int row0 = m0 + wm * 64 + rt * 16 + quad * 4;
                int bb = row0 >> 10, tok = row0 & 1023;
                bf16x4 pkk;
#pragma unroll
                for (int r = 0; r < 4; r++) pkk[r] = (__bf16)(acc[rt][ct][r] + bs);
                *(bf16x4*)&vtb[((size_t)(bb * NH + hh) * 64 + hd) * 1024 + tok] = pkk;
            }
        } else {
            float mult = (QKV && col < 768) ? CS : 1.0f;
#pragma unroll
            for (int rt = 0; rt < 4; rt++) {
#pragma unroll
                for (int r = 0; r < 4; r++) {
                    int row = m0 + wm * 64 + rt * 16 + quad * 4 + r;
                    C[(size_t)row * Nn + col] = (OutT)((acc[rt][ct][r] + bs) * mult);
                }
            }
        }
    }
}

// ---------------- flash attention, key-partitioned waves ----------------
// Block = 64 qrows of one (b,h); wave w owns keys [kt*64+w*16, +16) each iter.
// S^T = K_sub·Q^T (16x16x32): C/D row=quad*4+r=key matches the k-layout of the
// zero-padded-K PV mfma, so P feeds PV straight from registers (no LDS).
// O^T_partial = V^T_sub·P^T via K=32 mfma with A upper-half zeros, B duplicated.
// Quiet softmax exact identity: out = p / (max(p) + sum(p)), p = 2^(s_scaled).
__global__ __launch_bounds__(256) void k_attn(const __bf16* __restrict__ qkv,
                                              const __bf16* __restrict__ vt,
                                              __bf16* __restrict__ ctx) {
    __shared__ __align__(16) unsigned char smem[34816];
    __bf16* Ks = (__bf16*)smem;                    // [key64][hd64], 8KB, swizzled
    __bf16* Vs = (__bf16*)(smem + 8192);           // [hd64][key64], 8KB, swizzled
    float* buf0 = (float*)smem;                    // overlays Ks+Vs after loop
    float* buf1 = (float*)(smem + 16384);          // 16KB
    float* Lsum = (float*)(smem + 32768);          // [4][64]
    float* Pmax = (float*)(smem + 32768 + 1024);   // [4][64]

    int t = threadIdx.x, lane = t & 63, w = t >> 6;
    int quad = lane >> 4, n16 = lane & 15;
    // XCD-pinned swizzle: batch = id&7 pins each batch's K/V to one XCD's L2
    int id = blockIdx.x;
    int bB = id & 7;
    int seq = id >> 3;
    int h = seq % 12;
    int qt = seq / 12;
    int q0 = qt * 64;
    int bh = bB * NH + h;

    // Q fragments (B-operand): qf[ng][kfi]; Q pre-scaled by CS in GEMM epilogue
    bf16x8 qf[4][2];
    {
        const __bf16* qbase = qkv + (size_t)(bB * NSEQ + q0 + n16) * NQKV + h * 64 + quad * 8;
#pragma unroll
        for (int ng = 0; ng < 4; ng++)
#pragma unroll
            for (int kfi = 0; kfi < 2; kfi++)
                qf[ng][kfi] = *(const bf16x8*)(qbase + (size_t)(ng * 16) * NQKV + kfi * 32);
    }

    // staging induction pointers (wave stages rows w*16..w*16+15 of each tile)
    int srow0 = w * 16 + (lane >> 3);
    int pc = lane & 7;
    const __bf16* kg[2]; const __bf16* vg[2];
    __bf16* kl[2]; __bf16* vl[2];
#pragma unroll
    for (int ii = 0; ii < 2; ii++) {
        int rowl = srow0 + ii * 8;
        int c = pc ^ (rowl & 7);
        kg[ii] = qkv + (size_t)(bB * NSEQ + rowl) * NQKV + 768 + h * 64 + c * 8;
        vg[ii] = vt + (size_t)(bh * 64 + rowl) * NSEQ + c * 8;
        kl[ii] = &Ks[rowl * 64 + pc * 8];
        vl[ii] = &Vs[rowl * 64 + pc * 8];
    }

    floatx4 acc[4][4] = {};   // O^T partial: [mg=hd group][ng=qrow group]
    float rs[4] = {0.f, 0.f, 0.f, 0.f};   // sum(p) per qrow ng*16+n16, this wave's keys
    float pm[4] = {0.f, 0.f, 0.f, 0.f};   // max(p) likewise

    for (int kt = 0; kt < 16; kt++) {
        __syncthreads();
#pragma unroll
        for (int ii = 0; ii < 2; ii++) {
            async_copy16(kl[ii], kg[ii]);
            async_copy16(vl[ii], vg[ii]);
            kg[ii] += 64 * NQKV;
            vg[ii] += 64;
        }
        __builtin_amdgcn_s_waitcnt(0);  // drain global_load_lds before barrier
        __syncthreads();

        // K fragments (A-operand): wave's 16 keys, row = w*16+n16
        bf16x8 kf[2];
#pragma unroll
        for (int kfi = 0; kfi < 2; kfi++)
            kf[kfi] = *(const bf16x8*)&Ks[(w * 16 + n16) * 64 + ((quad + 4 * kfi) ^ (n16 & 7)) * 8];

        // S^T: lane holds keys quad*4+r (wave-local), qrows ng*16+n16
        floatx4 s[4] = {};
#pragma unroll
        for (int ng = 0; ng < 4; ng++)
#pragma unroll
            for (int kfi = 0; kfi < 2; kfi++)
                s[ng] = mfma16(kf[kfi], qf[ng][kfi], s[ng]);

        // p = 2^s (Q pre-scaled); accumulate per-lane sum & max; pack duplicated
        bf16x8 bp[4];
#pragma unroll
        for (int ng = 0; ng < 4; ng++) {
#pragma unroll
            for (int r = 0; r < 4; r++) {
                float p = exp2f(s[ng][r]);
                rs[ng] += p;
                pm[ng] = fmaxf(pm[ng], p);
                __bf16 pb = (__bf16)p;
                bp[ng][r] = pb;
                bp[ng][r + 4] = pb;
            }
        }

        // V^T fragments (A-operand), keys w*16+quad*4..+3, upper k half zero
        bf16x8 vf[4];
#pragma unroll
        for (int mg = 0; mg < 4; mg++) {
            int row = mg * 16 + n16;
            int C16 = (w * 2 + (quad >> 1)) ^ (row & 7);
            bf16x4 v4 = *(const bf16x4*)&Vs[row * 64 + C16 * 8 + (quad & 1) * 4];
            bf16x8 v8 = {v4[0], v4[1], v4[2], v4[3],
                         (__bf16)0.f, (__bf16)0.f, (__bf16)0.f, (__bf16)0.f};
            vf[mg] = v8;
        }

        // O^T += V^T_sub · P^T_sub (effective K=16 via zero padding)
#pragma unroll
        for (int mg = 0; mg < 4; mg++)
#pragma unroll
            for (int ng = 0; ng < 4; ng++)
                acc[mg][ng] = mfma16(vf[mg], bp[ng], acc[mg][ng]);
    }

    // reduce sum/max across quads (quads held disjoint keys)
#pragma unroll
    for (int ng = 0; ng < 4; ng++) {
        rs[ng] += __shfl_xor(rs[ng], 16);
        rs[ng] += __shfl_xor(rs[ng], 32);
        pm[ng] = fmaxf(pm[ng], __shfl_xor(pm[ng], 16));
        pm[ng] = fmaxf(pm[ng], __shfl_xor(pm[ng], 32));
    }
    if (lane < 16) {
#pragma unroll
        for (int ng = 0; ng < 4; ng++) {
            Lsum[w * 64 + ng * 16 + lane] = rs[ng];
            Pmax[w * 64 + ng * 16 + lane] = pm[ng];
        }
    }
    __syncthreads();  // also retires last iter's Ks/Vs reads before buf0 reuse

    // cross-wave O reduction: waves 0,1 write buf0/buf1; waves 2,3 add in
    // addr swizzle col' = qrow ^ (hd&31) keeps the transposed read 2-way
    float* mybuf = (w & 1) ? buf1 : buf0;
    if (w < 2) {
#pragma unroll
        for (int mg = 0; mg < 4; mg++)
#pragma unroll
            for (int ng = 0; ng < 4; ng++)
#pragma unroll
                for (int r = 0; r < 4; r++) {
                    int hd = mg * 16 + quad * 4 + r;
                    mybuf[hd * 64 + ((ng * 16 + n16) ^ (hd & 31))] = acc[mg][ng][r];
                }
    }
    __syncthreads();
    if (w >= 2) {
#pragma unroll
        for (int mg = 0; mg < 4; mg++)
#pragma unroll
            for (int ng = 0; ng < 4; ng++)
#pragma unroll
                for (int r = 0; r < 4; r++) {
                    int hd = mg * 16 + quad * 4 + r;
                    int a = hd * 64 + ((ng * 16 + n16) ^ (hd & 31));
                    mybuf[a] += acc[mg][ng][r];
                }
    }
    __syncthreads();

    // final: out[qrow][hd] = (buf0+buf1) / (pmax + l); coalesced 32B stores
    int qrow = w * 16 + (lane >> 2);
    int hdb = (lane & 3) * 16;
    float l = Lsum[qrow] + Lsum[64 + qrow] + Lsum[128 + qrow] + Lsum[192 + qrow];
    float pmx = fmaxf(fmaxf(Pmax[qrow], Pmax[64 + qrow]),
                      fmaxf(Pmax[128 + qrow], Pmax[192 + qrow]));
    float invd = 1.f / (pmx + l);
    bf16x8 o0, o1;
#pragma unroll
    for (int j = 0; j < 8; j++) {
        int hd = hdb + j;
        int a = hd * 64 + (qrow ^ (hd & 31));
        o0[j] = (__bf16)((buf0[a] + buf1[a]) * invd);
    }
#pragma unroll
    for (int j = 8; j < 16; j++) {
        int hd = hdb + j;
        int a = hd * 64 + (qrow ^ (hd & 31));
        o1[j - 8] = (__bf16)((buf0[a] + buf1[a]) * invd);
    }
    __bf16* dst = ctx + (size_t)(bB * NSEQ + q0 + qrow) * DMODEL + h * 64 + hdb;
    *(bf16x8*)dst = o0;
    *(bf16x8*)(dst + 8) = o1;
}

extern "C" void kernel_launch(void* const* d_in, const int* in_sizes, int n_in,
                              void* d_out, int out_size, void* d_ws, size_t ws_size,
                              hipStream_t stream) {
    (void)in_sizes; (void)n_in; (void)out_size;
    const float* x  = (const float*)d_in[0];
    const float* Wq = (const float*)d_in[1];
    const float* bq = (const float*)d_in[2];
    const float* Wk = (const float*)d_in[3];
    const float* bk = (const float*)d_in[4];
    const float* Wv = (const float*)d_in[5];
    const float* bv = (const float*)d_in[6];
    const float* Wo = (const float*)d_in[7];
    const float* bo = (const float*)d_in[8];
    float* out = (float*)d_out;

    char* ws = (char*)d_ws;
    size_t off = 0;
    auto alloc = [&](size_t bytes) {
        void* p = ws + off;
        off += (bytes + 255) & ~(size_t)255;
        return p;
    };
    __bf16* xb    = (__bf16*)alloc((size_t)MTOK * DMODEL * 2);   // 12.6 MB (reused as ctx)
    __bf16* wtqkv = (__bf16*)alloc((size_t)NQKV * DMODEL * 2);   // 3.5 MB
    __bf16* wto   = (__bf16*)alloc((size_t)DMODEL * DMODEL * 2); // 1.2 MB
    float*  bqkv  = (float*)alloc((size_t)NQKV * 4);
    __bf16* qkvb  = (__bf16*)alloc((size_t)MTOK * NQKV * 2);     // 37.7 MB (V region unused)
    __bf16* vtb   = (__bf16*)alloc((size_t)BB * NH * HD * NSEQ * 2); // 12.6 MB
    if (off > ws_size) return;  // workspace too small -> visible failure
    __bf16* ctx = xb;  // xb dead after QKV GEMM

    k_convert_x<<<dim3(6144), dim3(256), 0, stream>>>(x, xb);
    k_bias<<<dim3(9), dim3(256), 0, stream>>>(bq, bk, bv, bqkv);
    k_transpose_w<<<dim3(24, 24, 4), dim3(256), 0, stream>>>(Wq, Wk, Wv, Wo, wtqkv, wto);
    k_gemm<__bf16, true><<<dim3(64, 18), dim3(256), 0, stream>>>(xb, wtqkv, bqkv, qkvb, NQKV, vtb);
    k_attn<<<dim3(1536), dim3(256), 0, stream>>>(qkvb, vtb, ctx);
    k_gemm<float, false><<<dim3(64, 6), dim3(256), 0, stream>>>(ctx, wto, bo, out, DMODEL, nullptr);
}

// Round 4
// 220.819 us; speedup vs baseline: 1.0799x; 1.0799x over previous
//
#include <hip/hip_runtime.h>
#include <cstdint>

#define DEV __device__ __forceinline__

typedef __bf16 bf16x4 __attribute__((ext_vector_type(4)));
typedef __bf16 bf16x8 __attribute__((ext_vector_type(8)));
typedef float  floatx4 __attribute__((ext_vector_type(4)));
typedef short  short4v __attribute__((ext_vector_type(4)));

constexpr int BB = 8, NSEQ = 1024, DMODEL = 768, NH = 12, HD = 64;
constexpr int MTOK = BB * NSEQ;   // 8192 tokens
constexpr int NQKV = 3 * DMODEL;  // 2304
constexpr float CS = 0.18033688011112042f;  // (1/sqrt(64)) * log2(e), folded into Q

DEV void async_copy16(void* lds, const void* g) {
    // global -> LDS direct copy, 16B/lane. LDS dest must be wave-base + lane*16.
    __builtin_amdgcn_global_load_lds(
        (__attribute__((address_space(1))) void*)(const_cast<void*>(g)),
        (__attribute__((address_space(3))) void*)lds,
        16, 0, 0);
}

DEV floatx4 mfma16x32(bf16x8 a, bf16x8 b, floatx4 c) {
    return __builtin_amdgcn_mfma_f32_16x16x32_bf16(a, b, c, 0, 0, 0);
}
DEV floatx4 mfma16x16(bf16x4 a, bf16x4 b, floatx4 c) {
    // K=16 bf16 MFMA: operand k = quad*4+j  == S^T C/D row layout (key=quad*4+r)
    return __builtin_amdgcn_mfma_f32_16x16x16bf16_1k(
        __builtin_bit_cast(short4v, a), __builtin_bit_cast(short4v, b), c, 0, 0, 0);
}

// ---------------- x fp32 -> bf16 ----------------
__global__ __launch_bounds__(256) void k_convert_x(const float* __restrict__ x,
                                                   __bf16* __restrict__ xb) {
    int i = (blockIdx.x * 256 + threadIdx.x) * 4;  // grid sized exactly
    float4 v = *(const float4*)(x + i);
    bf16x4 o;
    o[0] = (__bf16)v.x; o[1] = (__bf16)v.y; o[2] = (__bf16)v.z; o[3] = (__bf16)v.w;
    *(bf16x4*)(xb + i) = o;
}

// ---------------- bias concat (q|k|v) fp32 ----------------
__global__ __launch_bounds__(256) void k_bias(const float* __restrict__ bq,
                                              const float* __restrict__ bk,
                                              const float* __restrict__ bv,
                                              float* __restrict__ out) {
    int i = blockIdx.x * 256 + threadIdx.x;  // grid = 9 -> 2304 exact
    if (i < 768) out[i] = bq[i];
    else if (i < 1536) out[i] = bk[i - 768];
    else if (i < 2304) out[i] = bv[i - 1536];
}

// ---------------- W [K,N] fp32 -> Wt [N,K] bf16 (z: 0=q 1=k 2=v 3=o) ----------------
__global__ __launch_bounds__(256) void k_transpose_w(const float* __restrict__ Wq,
                                                     const float* __restrict__ Wk,
                                                     const float* __restrict__ Wv,
                                                     const float* __restrict__ Wo,
                                                     __bf16* __restrict__ wtqkv,
                                                     __bf16* __restrict__ wto) {
    __shared__ float tile[32][33];
    int z = blockIdx.z;
    const float* W = (z == 0) ? Wq : (z == 1) ? Wk : (z == 2) ? Wv : Wo;
    int k0 = blockIdx.x * 32, n0 = blockIdx.y * 32;
    int tx = threadIdx.x & 31, ty = threadIdx.x >> 5;
#pragma unroll
    for (int p = 0; p < 4; p++)
        tile[ty + 8 * p][tx] = W[(size_t)(k0 + ty + 8 * p) * 768 + n0 + tx];
    __syncthreads();
    __bf16* out = (z < 3) ? (wtqkv + (size_t)z * 768 * 768) : wto;
#pragma unroll
    for (int p = 0; p < 4; p++)
        out[(size_t)(n0 + ty + 8 * p) * 768 + k0 + tx] = (__bf16)tile[tx][ty + 8 * p];
}

// ---------------- GEMM: C[M,Nn] = A[M,768] @ Bt[Nn,768]^T + bias ----------------
// BM=BN=128, BK=64, 4 waves each 64x64 (4x4 acc of 16x16x32 MFMA).
// QKV=true: scale Q cols by CS; route V cols (>=1536) transposed into vtb[b,h,hd,tok].
template <typename OutT, bool QKV>
__global__ __launch_bounds__(256) void k_gemm(const __bf16* __restrict__ A,
                                              const __bf16* __restrict__ Bt,
                                              const float* __restrict__ bias,
                                              OutT* __restrict__ C, int Nn,
                                              __bf16* __restrict__ vtb) {
    __shared__ __align__(16) __bf16 As[128 * 64];
    __shared__ __align__(16) __bf16 Bs[128 * 64];
    int t = threadIdx.x, lane = t & 63, w = t >> 6;
    int quad = lane >> 4, n16 = lane & 15;
    int wm = w & 1, wn = w >> 1;
    int m0 = blockIdx.x * 128, n0 = blockIdx.y * 128;
    floatx4 acc[4][4] = {};

    for (int k0 = 0; k0 < 768; k0 += 64) {
        __syncthreads();
#pragma unroll
        for (int i = 0; i < 4; i++) {  // stage A tile 128x64 (16KB)
            int off = t + i * 256;
            int row = off >> 3, pc = off & 7;
            int c = pc ^ (row & 7);
            async_copy16(&As[row * 64 + pc * 8],
                         &A[(size_t)(m0 + row) * 768 + k0 + c * 8]);
        }
#pragma unroll
        for (int i = 0; i < 4; i++) {  // stage B tile 128x64
            int off = t + i * 256;
            int row = off >> 3, pc = off & 7;
            int c = pc ^ (row & 7);
            async_copy16(&Bs[row * 64 + pc * 8],
                         &Bt[(size_t)(n0 + row) * 768 + k0 + c * 8]);
        }
        __builtin_amdgcn_s_waitcnt(0);  // drain global_load_lds before barrier
        __syncthreads();
#pragma unroll
        for (int kfi = 0; kfi < 2; kfi++) {
            bf16x8 a[4], bfr[4];
#pragma unroll
            for (int rt = 0; rt < 4; rt++) {
                int row = wm * 64 + rt * 16 + n16;
                a[rt] = *(const bf16x8*)&As[row * 64 + ((quad + 4 * kfi) ^ (row & 7)) * 8];
            }
#pragma unroll
            for (int ct = 0; ct < 4; ct++) {
                int row = wn * 64 + ct * 16 + n16;
                bfr[ct] = *(const bf16x8*)&Bs[row * 64 + ((quad + 4 * kfi) ^ (row & 7)) * 8];
            }
#pragma unroll
            for (int rt = 0; rt < 4; rt++)
#pragma unroll
                for (int ct = 0; ct < 4; ct++)
                    acc[rt][ct] = mfma16x32(a[rt], bfr[ct], acc[rt][ct]);
        }
    }
    // epilogue: C/D layout col=lane&15, row=quad*4+reg
#pragma unroll
    for (int ct = 0; ct < 4; ct++) {
        int col = n0 + wn * 64 + ct * 16 + n16;
        float bs = bias[col];
        if (QKV && col >= 1536) {
            // V region -> vtb[b,h,hd,tok], 4 consecutive tokens per b64 store
            int vcol = col - 1536;
            int hh = vcol >> 6, hd = vcol & 63;
#pragma unroll
            for (int rt = 0; rt < 4; rt++) {
                int row0 = m0 + wm * 64 + rt * 16 + quad * 4;
                int bb = row0 >> 10, tok = row0 & 1023;
                bf16x4 pkk;
#pragma unroll
                for (int r = 0; r < 4; r++) pkk[r] = (__bf16)(acc[rt][ct][r] + bs);
                *(bf16x4*)&vtb[((size_t)(bb * NH + hh) * 64 + hd) * 1024 + tok] = pkk;
            }
        } else {
            float mult = (QKV && col < 768) ? CS : 1.0f;
#pragma unroll
            for (int rt = 0; rt < 4; rt++) {
#pragma unroll
                for (int r = 0; r < 4; r++) {
                    int row = m0 + wm * 64 + rt * 16 + quad * 4 + r;
                    C[(size_t)row * Nn + col] = (OutT)((acc[rt][ct][r] + bs) * mult);
                }
            }
        }
    }
}

// ---------------- flash attention, key-partitioned waves, K=16 PV ----------------
// Block = 32 qrows of one (b,h); wave w owns keys [kt*64+w*16, +16) each iter.
// S^T = K_sub·Q^T (16x16x32): C/D row = quad*4+r = key  ==  operand k-layout of
// the K=16 MFMA, so P feeds PV register-direct (convert to bf16, no LDS/shuffle).
// O^T_partial = V^T_sub·P^T via mfma_f32_16x16x16_bf16 (full efficiency).
// Quiet softmax exact identity: out = p / (max(p) + sum(p)), p = 2^(s_scaled).
__global__ __launch_bounds__(256) void k_attn(const __bf16* __restrict__ qkv,
                                              const __bf16* __restrict__ vt,
                                              __bf16* __restrict__ ctx) {
    __shared__ __align__(16) unsigned char smem[26112];
    __bf16* Ks = (__bf16*)smem;                    // [key64][hd64], 8KB, swizzled
    __bf16* Vs = (__bf16*)(smem + 8192);           // [hd64][key64], 8KB, swizzled
    float* buf0 = (float*)smem;                    // overlays Ks/Vs after loop (8.7KB)
    float* buf1 = (float*)(smem + 16384);          // 8.7KB
    float* Lsum = (float*)(smem + 25088);          // [4][32]
    float* Pmax = (float*)(smem + 25600);          // [4][32]

    int t = threadIdx.x, lane = t & 63, w = t >> 6;
    int quad = lane >> 4, n16 = lane & 15;
    // XCD-pinned swizzle: batch = id&7 pins each batch's K/V to one XCD's L2
    int id = blockIdx.x;
    int bB = id & 7;
    int seq = id >> 3;
    int h = seq % 12;
    int qt = seq / 12;
    int q0 = qt * 32;
    int bh = bB * NH + h;

    // Q fragments (B-operand of 16x16x32): qf[ng][kfi]; Q pre-scaled by CS in GEMM
    bf16x8 qf[2][2];
    {
        const __bf16* qbase = qkv + (size_t)(bB * NSEQ + q0 + n16) * NQKV + h * 64 + quad * 8;
#pragma unroll
        for (int ng = 0; ng < 2; ng++)
#pragma unroll
            for (int kfi = 0; kfi < 2; kfi++)
                qf[ng][kfi] = *(const bf16x8*)(qbase + (size_t)(ng * 16) * NQKV + kfi * 32);
    }

    // staging induction pointers (wave stages rows w*16..w*16+15 of each tile)
    int srow0 = w * 16 + (lane >> 3);
    int pc = lane & 7;
    const __bf16* kg[2]; const __bf16* vg[2];
    __bf16* kl[2]; __bf16* vl[2];
#pragma unroll
    for (int ii = 0; ii < 2; ii++) {
        int rowl = srow0 + ii * 8;
        int c = pc ^ (rowl & 7);
        kg[ii] = qkv + (size_t)(bB * NSEQ + rowl) * NQKV + 768 + h * 64 + c * 8;
        vg[ii] = vt + (size_t)(bh * 64 + rowl) * NSEQ + c * 8;
        kl[ii] = &Ks[rowl * 64 + pc * 8];
        vl[ii] = &Vs[rowl * 64 + pc * 8];
    }

    floatx4 acc[4][2] = {};               // O^T partial: [mg=hd group][ng=qrow group]
    float rs[2] = {0.f, 0.f};             // sum(p) per qrow ng*16+n16, wave's keys
    float pm[2] = {0.f, 0.f};             // max(p) likewise

    for (int kt = 0; kt < 16; kt++) {
        __syncthreads();
#pragma unroll
        for (int ii = 0; ii < 2; ii++) {
            async_copy16(kl[ii], kg[ii]);
            async_copy16(vl[ii], vg[ii]);
            kg[ii] += 64 * NQKV;
            vg[ii] += 64;
        }
        __builtin_amdgcn_s_waitcnt(0);  // drain global_load_lds before barrier
        __syncthreads();

        // K fragments (A-operand): wave's 16 keys, row = w*16+n16
        bf16x8 kf[2];
#pragma unroll
        for (int kfi = 0; kfi < 2; kfi++)
            kf[kfi] = *(const bf16x8*)&Ks[(w * 16 + n16) * 64 + (((kfi * 4 + quad)) ^ (n16 & 7)) * 8];

        // V^T fragments (A-operand of K=16 mfma): hd = mg*16+n16, keys w*16+quad*4..+3
        bf16x4 vf[4];
#pragma unroll
        for (int mg = 0; mg < 4; mg++) {
            int row = mg * 16 + n16;
            int cc = (w * 2 + (quad >> 1)) ^ (row & 7);
            vf[mg] = *(const bf16x4*)&Vs[row * 64 + cc * 8 + (quad & 1) * 4];
        }

        // S^T: lane holds keys w*16+quad*4+r, qrows q0+ng*16+n16
        floatx4 s[2] = {};
#pragma unroll
        for (int ng = 0; ng < 2; ng++)
#pragma unroll
            for (int kfi = 0; kfi < 2; kfi++)
                s[ng] = mfma16x32(kf[kfi], qf[ng][kfi], s[ng]);

        // p = 2^s (Q pre-scaled); per-lane sum & max; bf16 for PV B-operand
        bf16x4 pb[2];
#pragma unroll
        for (int ng = 0; ng < 2; ng++) {
#pragma unroll
            for (int r = 0; r < 4; r++) {
                float p = exp2f(s[ng][r]);
                rs[ng] += p;
                pm[ng] = fmaxf(pm[ng], p);
                pb[ng][r] = (__bf16)p;
            }
        }

        // O^T += V^T_sub · P^T_sub, K=16 register-direct
#pragma unroll
        for (int mg = 0; mg < 4; mg++)
#pragma unroll
            for (int ng = 0; ng < 2; ng++)
                acc[mg][ng] = mfma16x16(vf[mg], pb[ng], acc[mg][ng]);
    }

    // reduce sum/max across quads (quads held disjoint keys)
#pragma unroll
    for (int ng = 0; ng < 2; ng++) {
        rs[ng] += __shfl_xor(rs[ng], 16);
        rs[ng] += __shfl_xor(rs[ng], 32);
        pm[ng] = fmaxf(pm[ng], __shfl_xor(pm[ng], 16));
        pm[ng] = fmaxf(pm[ng], __shfl_xor(pm[ng], 32));
    }
    if (quad < 2) {
        Lsum[w * 32 + quad * 16 + n16] = quad ? rs[1] : rs[0];
        Pmax[w * 32 + quad * 16 + n16] = quad ? pm[1] : pm[0];
    }
    __syncthreads();  // retires Ks/Vs reads before buf0 (overlay) writes

    // cross-wave O reduction: b128 stores, [qrow][hd] stride 68 (2-way = free)
    float* mybuf = (w & 1) ? buf1 : buf0;
    if (w < 2) {
#pragma unroll
        for (int mg = 0; mg < 4; mg++)
#pragma unroll
            for (int ng = 0; ng < 2; ng++)
                *(floatx4*)&mybuf[(ng * 16 + n16) * 68 + mg * 16 + quad * 4] = acc[mg][ng];
    }
    __syncthreads();
    if (w >= 2) {
#pragma unroll
        for (int mg = 0; mg < 4; mg++)
#pragma unroll
            for (int ng = 0; ng < 2; ng++) {
                float* p = &mybuf[(ng * 16 + n16) * 68 + mg * 16 + quad * 4];
                floatx4 cur = *(const floatx4*)p;
                *(floatx4*)p = cur + acc[mg][ng];
            }
    }
    __syncthreads();

    // final: out[qrow][hd] = (buf0+buf1) / (pmax + l); coalesced 16B stores
    int qrow = t >> 3;
    int hh = (t & 7) * 8;
    float l = Lsum[qrow] + Lsum[32 + qrow] + Lsum[64 + qrow] + Lsum[96 + qrow];
    float pmx = fmaxf(fmaxf(Pmax[qrow], Pmax[32 + qrow]),
                      fmaxf(Pmax[64 + qrow], Pmax[96 + qrow]));
    float invd = 1.f / (pmx + l);
    floatx4 v0 = *(const floatx4*)&buf0[qrow * 68 + hh];
    floatx4 v1 = *(const floatx4*)&buf0[qrow * 68 + hh + 4];
    floatx4 u0 = *(const floatx4*)&buf1[qrow * 68 + hh];
    floatx4 u1 = *(const floatx4*)&buf1[qrow * 68 + hh + 4];
    bf16x8 o;
#pragma unroll
    for (int j = 0; j < 4; j++) o[j] = (__bf16)((v0[j] + u0[j]) * invd);
#pragma unroll
    for (int j = 0; j < 4; j++) o[j + 4] = (__bf16)((v1[j] + u1[j]) * invd);
    __bf16* dst = ctx + (size_t)(bB * NSEQ + q0 + qrow) * DMODEL + h * 64 + hh;
    *(bf16x8*)dst = o;
}

extern "C" void kernel_launch(void* const* d_in, const int* in_sizes, int n_in,
                              void* d_out, int out_size, void* d_ws, size_t ws_size,
                              hipStream_t stream) {
    (void)in_sizes; (void)n_in; (void)out_size;
    const float* x  = (const float*)d_in[0];
    const float* Wq = (const float*)d_in[1];
    const float* bq = (const float*)d_in[2];
    const float* Wk = (const float*)d_in[3];
    const float* bk = (const float*)d_in[4];
    const float* Wv = (const float*)d_in[5];
    const float* bv = (const float*)d_in[6];
    const float* Wo = (const float*)d_in[7];
    const float* bo = (const float*)d_in[8];
    float* out = (float*)d_out;

    char* ws = (char*)d_ws;
    size_t off = 0;
    auto alloc = [&](size_t bytes) {
        void* p = ws + off;
        off += (bytes + 255) & ~(size_t)255;
        return p;
    };
    __bf16* xb    = (__bf16*)alloc((size_t)MTOK * DMODEL * 2);   // 12.6 MB (reused as ctx)
    __bf16* wtqkv = (__bf16*)alloc((size_t)NQKV * DMODEL * 2);   // 3.5 MB
    __bf16* wto   = (__bf16*)alloc((size_t)DMODEL * DMODEL * 2); // 1.2 MB
    float*  bqkv  = (float*)alloc((size_t)NQKV * 4);
    __bf16* qkvb  = (__bf16*)alloc((size_t)MTOK * NQKV * 2);     // 37.7 MB (V region unused)
    __bf16* vtb   = (__bf16*)alloc((size_t)BB * NH * HD * NSEQ * 2); // 12.6 MB
    if (off > ws_size) return;  // workspace too small -> visible failure
    __bf16* ctx = xb;  // xb dead after QKV GEMM

    k_convert_x<<<dim3(6144), dim3(256), 0, stream>>>(x, xb);
    k_bias<<<dim3(9), dim3(256), 0, stream>>>(bq, bk, bv, bqkv);
    k_transpose_w<<<dim3(24, 24, 4), dim3(256), 0, stream>>>(Wq, Wk, Wv, Wo, wtqkv, wto);
    k_gemm<__bf16, true><<<dim3(64, 18), dim3(256), 0, stream>>>(xb, wtqkv, bqkv, qkvb, NQKV, vtb);
    k_attn<<<dim3(3072), dim3(256), 0, stream>>>(qkvb, vtb, ctx);
    k_gemm<float, false><<<dim3(64, 6), dim3(256), 0, stream>>>(ctx, wto, bo, out, DMODEL, nullptr);
}